// Round 4
// baseline (715.688 us; speedup 1.0000x reference)
//
#include <hip/hip_runtime.h>
#include <math.h>

#define NN 20000
#define EE 640000
#define TILE 32                  // edges per wave; EE % TILE == 0 exactly
#define NWAVES (EE / TILE)       // 20000 waves, perfectly balanced
#define STEPS (TILE / 2)         // 16 steps; 2 edges per step (one per half-wave)

#define OUT_F4 (NN * 32)         // out is NN*128 floats = 640,000 float4
#define L_F4   (NN * 2)          // lsum is NN*8 floats  =  40,000 float4
#define Z_TOT  (OUT_F4 + L_F4)

// workspace layout: [ lsum : NN*8 floats ][ w : EE*8 floats ]  (~21.1 MB)
#define W_OFF (NN * 8)

// Zero the output accumulator and per-(node,head) softmax denominators.
__global__ __launch_bounds__(256)
void zero_accum(float4* __restrict__ out4, float4* __restrict__ l4) {
    int i = blockIdx.x * 256 + threadIdx.x;
    float4 z = make_float4(0.f, 0.f, 0.f, 0.f);
    if (i < OUT_F4) out4[i] = z;
    else if (i < Z_TOT) l4[i - OUT_F4] = z;
}

// Cross-lane add within the 4-lane head group, pure VALU (DPP quad_perm).
template<int CTRL>
__device__ __forceinline__ float dpp_add(float x) {
    int y = __builtin_amdgcn_mov_dpp(__float_as_int(x), CTRL, 0xF, 0xF, false);
    return x + __int_as_float(y);
}

// ---------------- Phase A: scores ----------------
// Pure single-stream: read key (328 MB), write per-(edge,head) weight w
// (20.5 MB). No atomics, no cross-iteration dependencies -> every load can be
// in flight. launch_bounds(256,4) gives the register budget (<=128 VGPR) for a
// real depth-4 pipeline (R1-R3 lesson: without it the compiler targets 40
// VGPRs and collapses the pipeline to depth 1).
//
// Softmax max-subtraction omitted (shift-invariant; scores ~N(0,0.35), exp in
// [0.05,7]) so w is order-independent and phases can be split.
__global__ __launch_bounds__(256, 4)
void score_pass(const float* __restrict__ key,   // (E,128)
                const float* __restrict__ q0,    // (N,32)
                const float* __restrict__ q1,    // (N,96)
                const int*   __restrict__ dst,   // (E,) sorted
                float*       __restrict__ w)     // (E,8)
{
    const int wid  = blockIdx.x * 4 + (threadIdx.x >> 6);
    const int lane = threadIdx.x & 63;
    const int s    = lane >> 5;
    const int cl   = lane & 31;
    const int t    = wid * TILE;

    const int dreg = dst[t + cl];
    // bit i (i>=2, low 32) of ballot = dst[t+i] != dst[t+i-2]
    const int prev2 = __shfl(dreg, lane - 2);
    const unsigned long long bal = __ballot(dreg != prev2);
    const unsigned mask2  = (unsigned)bal & 0xFFFFFFFCu;
    const unsigned mybits = mask2 >> s;            // step j tests bit 2j

    const float scale = 0.08838834764831845f;      // 1/sqrt(128)
    int cur_n = __shfl(dreg, s * 33);              // dst[t+s]
    float4 qv;
    qv.x = q0[cur_n * 32 + cl];
    qv.y = q1[cur_n * 96 + cl * 3 + 0];
    qv.z = q1[cur_n * 96 + cl * 3 + 1];
    qv.w = q1[cur_n * 96 + cl * 3 + 2];

    const float* kp = key + (size_t)(t + s) * 128 + cl * 4;
    float4 kb0 = *(const float4*)(kp);
    float4 kb1 = *(const float4*)(kp + 256);
    float4 kb2 = *(const float4*)(kp + 512);
    float4 kb3 = *(const float4*)(kp + 768);

#define ASTEP(J, KB)                                                           \
    {                                                                          \
        const float4 kc = KB;                                                  \
        if ((J) + 4 < STEPS) KB = *(const float4*)(kp + ((J) + 4) * 256);      \
        if ((J) > 0 && (mybits & (1u << (2 * (J))))) {                         \
            cur_n = __shfl(dreg, (s << 5) + 2 * (J) + s);                      \
            qv.x = q0[cur_n * 32 + cl];                                        \
            qv.y = q1[cur_n * 96 + cl * 3 + 0];                                \
            qv.z = q1[cur_n * 96 + cl * 3 + 1];                                \
            qv.w = q1[cur_n * 96 + cl * 3 + 2];                                \
        }                                                                      \
        float p = fmaf(kc.x, qv.x, fmaf(kc.y, qv.y, fmaf(kc.z, qv.z, kc.w * qv.w))); \
        p = dpp_add<0xB1>(p);                                                  \
        p = dpp_add<0x4E>(p);                                                  \
        const float wgt = __expf(p * scale);                                   \
        if ((cl & 3) == 0) w[(size_t)(t + 2 * (J) + s) * 8 + (cl >> 2)] = wgt; \
    }

    ASTEP(0,  kb0) ASTEP(1,  kb1) ASTEP(2,  kb2) ASTEP(3,  kb3)
    ASTEP(4,  kb0) ASTEP(5,  kb1) ASTEP(6,  kb2) ASTEP(7,  kb3)
    ASTEP(8,  kb0) ASTEP(9,  kb1) ASTEP(10, kb2) ASTEP(11, kb3)
    ASTEP(12, kb0) ASTEP(13, kb1) ASTEP(14, kb2) ASTEP(15, kb3)
#undef ASTEP
}

// ---------------- Phase B: weighted value scatter ----------------
// Single main stream: read val (328 MB) + w (20.5 MB, cache-warm). Accumulate
// per-run in registers; flush runs with device-scope atomics (runs split
// across waves only at tile boundaries). Also accumulates the softmax
// denominator lsum from w - no extra traffic.
__global__ __launch_bounds__(256, 4)
void value_pass(const float* __restrict__ val,   // (E,128)
                const float* __restrict__ w,     // (E,8)
                const int*   __restrict__ dst,   // (E,) sorted
                float*       __restrict__ out,   // [N*32 | N*96] accumulators
                float*       __restrict__ lsum)  // (N,8)
{
    const int wid  = blockIdx.x * 4 + (threadIdx.x >> 6);
    const int lane = threadIdx.x & 63;
    const int s    = lane >> 5;
    const int cl   = lane & 31;
    const int t    = wid * TILE;

    const int dreg = dst[t + cl];
    const int prev2 = __shfl(dreg, lane - 2);
    const unsigned long long bal = __ballot(dreg != prev2);
    const unsigned mask2  = (unsigned)bal & 0xFFFFFFFCu;
    const unsigned mybits = mask2 >> s;

    int cur_n = __shfl(dreg, s * 33);

    const float* vp = val + (size_t)(t + s) * 128 + cl * 4;
    const float* wp = w + (size_t)(t + s) * 8 + (cl >> 2);

    float  lrun = 0.f;
    float4 acc  = make_float4(0.f, 0.f, 0.f, 0.f);

    float4 vb0 = *(const float4*)(vp);        float wb0 = wp[0];
    float4 vb1 = *(const float4*)(vp + 256);  float wb1 = wp[16];
    float4 vb2 = *(const float4*)(vp + 512);  float wb2 = wp[32];
    float4 vb3 = *(const float4*)(vp + 768);  float wb3 = wp[48];

#define BSTEP(J, VB, WB)                                                       \
    {                                                                          \
        const float4 vc = VB;                                                  \
        const float wc = WB;                                                   \
        if ((J) + 4 < STEPS) {                                                 \
            VB = *(const float4*)(vp + ((J) + 4) * 256);                       \
            WB = wp[((J) + 4) * 16];                                           \
        }                                                                      \
        if ((J) > 0 && (mybits & (1u << (2 * (J))))) {                         \
            atomicAdd(&out[cur_n * 32 + cl], acc.x);                           \
            float* o1 = out + NN * 32 + cur_n * 96 + cl * 3;                   \
            atomicAdd(o1 + 0, acc.y);                                          \
            atomicAdd(o1 + 1, acc.z);                                          \
            atomicAdd(o1 + 2, acc.w);                                          \
            if ((cl & 3) == 0) atomicAdd(&lsum[cur_n * 8 + (cl >> 2)], lrun);  \
            acc  = make_float4(0.f, 0.f, 0.f, 0.f);                            \
            lrun = 0.f;                                                        \
            cur_n = __shfl(dreg, (s << 5) + 2 * (J) + s);                      \
        }                                                                      \
        lrun += wc;                                                            \
        acc.x = fmaf(wc, vc.x, acc.x);                                         \
        acc.y = fmaf(wc, vc.y, acc.y);                                         \
        acc.z = fmaf(wc, vc.z, acc.z);                                         \
        acc.w = fmaf(wc, vc.w, acc.w);                                         \
    }

    BSTEP(0,  vb0, wb0) BSTEP(1,  vb1, wb1) BSTEP(2,  vb2, wb2) BSTEP(3,  vb3, wb3)
    BSTEP(4,  vb0, wb0) BSTEP(5,  vb1, wb1) BSTEP(6,  vb2, wb2) BSTEP(7,  vb3, wb3)
    BSTEP(8,  vb0, wb0) BSTEP(9,  vb1, wb1) BSTEP(10, vb2, wb2) BSTEP(11, vb3, wb3)
    BSTEP(12, vb0, wb0) BSTEP(13, vb1, wb1) BSTEP(14, vb2, wb2) BSTEP(15, vb3, wb3)
#undef BSTEP

    atomicAdd(&out[cur_n * 32 + cl], acc.x);
    float* o1 = out + NN * 32 + cur_n * 96 + cl * 3;
    atomicAdd(o1 + 0, acc.y);
    atomicAdd(o1 + 1, acc.z);
    atomicAdd(o1 + 2, acc.w);
    if ((cl & 3) == 0) atomicAdd(&lsum[cur_n * 8 + (cl >> 2)], lrun);
}

// Divide accumulators by the per-(node,head) denominator.
__global__ __launch_bounds__(256)
void finalize(float* __restrict__ out, const float* __restrict__ lsum) {
    const int i = blockIdx.x * 256 + threadIdx.x;   // 0 .. NN*32-1
    const int n = i >> 5;
    const int c = i & 31;
    const float li = lsum[n * 8 + (c >> 2)];
    const float inv = (li > 0.f) ? 1.0f / li : 0.0f;  // deg==0 node -> zeros
    out[i] *= inv;
    float* o1 = out + NN * 32 + (size_t)n * 96 + c * 3;
    o1[0] *= inv;
    o1[1] *= inv;
    o1[2] *= inv;
}

extern "C" void kernel_launch(void* const* d_in, const int* in_sizes, int n_in,
                              void* d_out, int out_size, void* d_ws, size_t ws_size,
                              hipStream_t stream) {
    const float* key = (const float*)d_in[0];
    const float* q0  = (const float*)d_in[1];
    const float* q1  = (const float*)d_in[2];
    const float* val = (const float*)d_in[3];
    const int*   dst = (const int*)d_in[4];
    float* out  = (float*)d_out;
    float* lsum = (float*)d_ws;             // NN*8 floats
    float* w    = (float*)d_ws + W_OFF;     // EE*8 floats (total ~21.1 MB)

    zero_accum<<<(Z_TOT + 255) / 256, 256, 0, stream>>>((float4*)out, (float4*)lsum);
    score_pass<<<NWAVES / 4, 256, 0, stream>>>(key, q0, q1, dst, w);
    value_pass<<<NWAVES / 4, 256, 0, stream>>>(val, w, dst, out, lsum);
    finalize<<<(NN * 32) / 256, 256, 0, stream>>>(out, lsum);
}